// Round 5
// baseline (301.998 us; speedup 1.0000x reference)
//
#include <hip/hip_runtime.h>

#define DEPTH 128
#define GPB 16        // graphs per block in the MLP kernel
#define CHUNK 977     // rows per pool block: ceil(2e6/2048) -> exactly 2048 blocks
#define MAXSEG 64     // max graph segments per chunk (realistic <= ~5)

typedef float f4 __attribute__((ext_vector_type(4)));

// Monotone float->uint map: f1 < f2  <=>  enc(f1) < enc(f2). 0 is the -inf sentinel.
__device__ __forceinline__ unsigned enc_f32(float f) {
    unsigned s = __float_as_uint(f);
    return (s & 0x80000000u) ? ~s : (s | 0x80000000u);
}
__device__ __forceinline__ float dec_f32(unsigned u) {
    return __uint_as_float((u & 0x80000000u) ? (u & 0x7fffffffu) : ~u);
}

// Kernel 0: zero/sentinel-init the merge buffers (ws is poisoned, not re-poisoned).
__global__ void init_kernel(float* __restrict__ sumbuf, unsigned* __restrict__ maxbuf,
                            int* __restrict__ cntbuf, int G) {
    int i = blockIdx.x * blockDim.x + threadIdx.x;
    int total = G * DEPTH;
    if (i < total) { sumbuf[i] = 0.f; maxbuf[i] = 0u; }
    if (i < G) cntbuf[i] = 0;
}

// Kernel 1: equal-work contiguous chunks. Each block streams CHUNK rows once,
// splits them into graph segments via a cooperative boundary scan (batch is
// sorted), accumulates sum/max per segment in registers, LDS-reduces, and
// atomically merges into global per-graph buffers.
__global__ __launch_bounds__(256) void pool_kernel(
    const f4* __restrict__ x4, const int* __restrict__ batch,
    float* __restrict__ sumbuf, unsigned* __restrict__ maxbuf,
    int* __restrict__ cntbuf, int N)
{
    const int tid = threadIdx.x;
    const int rg  = tid >> 5;   // row group 0..7
    const int d4  = tid & 31;   // float4 column 0..31
    const int c0  = blockIdx.x * CHUNK;
    const int c1  = (c0 + CHUNK < N) ? (c0 + CHUNK) : N;
    if (c0 >= N) return;

    // ---- cooperative segment-boundary scan (coalesced read of batch chunk) ----
    __shared__ int nb;
    __shared__ int bpos[MAXSEG + 1];
    if (tid == 0) nb = 0;
    __syncthreads();
    for (int i = c0 + tid; i < c1; i += 256) {
        bool bnd = (i == c0) || (batch[i] != batch[i - 1]);
        if (bnd) {
            int k = atomicAdd(&nb, 1);
            if (k < MAXSEG) bpos[k] = i;
        }
    }
    __syncthreads();
    const int ns = (nb < MAXSEG) ? nb : MAXSEG;
    if (tid == 0) {
        for (int a = 1; a < ns; ++a) {          // tiny insertion sort (ns <= ~5)
            int v = bpos[a]; int b = a - 1;
            while (b >= 0 && bpos[b] > v) { bpos[b + 1] = bpos[b]; --b; }
            bpos[b + 1] = v;
        }
        bpos[ns] = c1;
    }
    __syncthreads();

    __shared__ f4 redS[8][32];
    __shared__ f4 redM[8][32];

#define ACC(v, s, m) do { \
        (s) += (v); \
        (m).x = fmaxf((m).x, (v).x); (m).y = fmaxf((m).y, (v).y); \
        (m).z = fmaxf((m).z, (v).z); (m).w = fmaxf((m).w, (v).w); } while (0)

    for (int s = 0; s < ns; ++s) {
        const int bs = bpos[s], be = bpos[s + 1];

        f4 sum0 = (f4)(0.f), sum1 = sum0, sum2 = sum0, sum3 = sum0;
        f4 mx0 = (f4)(-INFINITY), mx1 = mx0, mx2 = mx0, mx3 = mx0;

        int r = bs + rg;
        for (; r + 24 < be; r += 32) {
            f4 v0 = x4[(size_t)(r)      * 32 + d4];
            f4 v1 = x4[(size_t)(r + 8)  * 32 + d4];
            f4 v2 = x4[(size_t)(r + 16) * 32 + d4];
            f4 v3 = x4[(size_t)(r + 24) * 32 + d4];
            ACC(v0, sum0, mx0); ACC(v1, sum1, mx1);
            ACC(v2, sum2, mx2); ACC(v3, sum3, mx3);
        }
        for (; r < be; r += 8) {
            f4 v = x4[(size_t)r * 32 + d4];
            ACC(v, sum0, mx0);
        }

        f4 sum = sum0 + sum1 + sum2 + sum3;
        f4 mx;
        mx.x = fmaxf(fmaxf(mx0.x, mx1.x), fmaxf(mx2.x, mx3.x));
        mx.y = fmaxf(fmaxf(mx0.y, mx1.y), fmaxf(mx2.y, mx3.y));
        mx.z = fmaxf(fmaxf(mx0.z, mx1.z), fmaxf(mx2.z, mx3.z));
        mx.w = fmaxf(fmaxf(mx0.w, mx1.w), fmaxf(mx2.w, mx3.w));

        redS[rg][d4] = sum;
        redM[rg][d4] = mx;
        __syncthreads();

        if (tid < 32) {
            f4 sr = redS[0][d4];
            f4 mr = redM[0][d4];
            #pragma unroll
            for (int i = 1; i < 8; ++i) {
                sr += redS[i][d4];
                f4 tm = redM[i][d4];
                mr.x = fmaxf(mr.x, tm.x); mr.y = fmaxf(mr.y, tm.y);
                mr.z = fmaxf(mr.z, tm.z); mr.w = fmaxf(mr.w, tm.w);
            }
            const int g = batch[bs];
            float*    sp = sumbuf + (size_t)g * DEPTH + d4 * 4;
            unsigned* mp = maxbuf + (size_t)g * DEPTH + d4 * 4;
            atomicAdd(&sp[0], sr.x); atomicAdd(&sp[1], sr.y);
            atomicAdd(&sp[2], sr.z); atomicAdd(&sp[3], sr.w);
            atomicMax(&mp[0], enc_f32(mr.x)); atomicMax(&mp[1], enc_f32(mr.y));
            atomicMax(&mp[2], enc_f32(mr.z)); atomicMax(&mp[3], enc_f32(mr.w));
            if (d4 == 0) atomicAdd(&cntbuf[g], be - bs);
        }
        __syncthreads();
    }
#undef ACC
}

// Kernel 2: MLP over merged pooled features, GPB graphs per block.
__global__ __launch_bounds__(256) void mlp_kernel(
    const float* __restrict__ sumbuf, const unsigned* __restrict__ maxbuf,
    const int* __restrict__ cntbuf,
    const float* __restrict__ W1, const float* __restrict__ b1,
    const float* __restrict__ W2, const float* __restrict__ b2,
    float* __restrict__ out, int G)
{
    __shared__ float h[GPB][3 * DEPTH];   // 24 KB
    __shared__ float a[GPB][DEPTH];       // 8 KB
    const int tid = threadIdx.x;
    const int g0  = blockIdx.x * GPB;

    for (int idx = tid; idx < GPB * DEPTH; idx += 256) {
        const int gl = idx >> 7, d = idx & 127;
        const int g  = g0 + gl;
        const float    sv = sumbuf[(size_t)g * DEPTH + d];
        const unsigned uv = maxbuf[(size_t)g * DEPTH + d];
        const int      c  = cntbuf[g];
        h[gl][d]             = (c > 0) ? dec_f32(uv) : 0.f;
        h[gl][DEPTH + d]     = sv / (float)(c > 1 ? c : 1);
        h[gl][2 * DEPTH + d] = sv;
    }
    __syncthreads();

    const int j  = tid & 127;               // output dim
    const int gh = (tid >> 7) * (GPB / 2);  // 0 or 8

    float acc[GPB / 2];
    #pragma unroll
    for (int i = 0; i < GPB / 2; ++i) acc[i] = b1[j];
    {
        const f4* w1r = reinterpret_cast<const f4*>(W1 + (size_t)j * 3 * DEPTH);
        for (int k = 0; k < 3 * DEPTH / 4; ++k) {
            f4 w = w1r[k];
            #pragma unroll
            for (int i = 0; i < GPB / 2; ++i) {
                f4 hv = reinterpret_cast<const f4*>(h[gh + i])[k];  // LDS broadcast
                acc[i] += w.x * hv.x + w.y * hv.y + w.z * hv.z + w.w * hv.w;
            }
        }
    }
    #pragma unroll
    for (int i = 0; i < GPB / 2; ++i)
        a[gh + i][j] = (acc[i] > 0.f) ? acc[i] : 0.01f * acc[i];
    __syncthreads();

    #pragma unroll
    for (int i = 0; i < GPB / 2; ++i) acc[i] = b2[j];
    {
        const f4* w2r = reinterpret_cast<const f4*>(W2 + (size_t)j * DEPTH);
        for (int k = 0; k < DEPTH / 4; ++k) {
            f4 w = w2r[k];
            #pragma unroll
            for (int i = 0; i < GPB / 2; ++i) {
                f4 av = reinterpret_cast<const f4*>(a[gh + i])[k];  // LDS broadcast
                acc[i] += w.x * av.x + w.y * av.y + w.z * av.z + w.w * av.w;
            }
        }
    }
    #pragma unroll
    for (int i = 0; i < GPB / 2; ++i) {
        const int g = g0 + gh + i;
        if (g < G) out[(size_t)g * DEPTH + j] = acc[i];
    }
}

extern "C" void kernel_launch(void* const* d_in, const int* in_sizes, int n_in,
                              void* d_out, int out_size, void* d_ws, size_t ws_size,
                              hipStream_t stream) {
    const float* x     = (const float*)d_in[0];
    const int*   batch = (const int*)d_in[1];
    const float* W1 = (const float*)d_in[3];
    const float* b1 = (const float*)d_in[4];
    const float* W2 = (const float*)d_in[5];
    const float* b2 = (const float*)d_in[6];
    float* out = (float*)d_out;

    const int N = in_sizes[0] / DEPTH;   // 2,000,000 nodes
    const int G = out_size / DEPTH;      // 4096 graphs

    float*    sumbuf = (float*)d_ws;                                    // G*128 f32
    unsigned* maxbuf = (unsigned*)((char*)d_ws + (size_t)G * DEPTH * 4); // G*128 u32
    int*      cntbuf = (int*)((char*)d_ws + (size_t)G * DEPTH * 8);      // G i32

    const int nchunks = (N + CHUNK - 1) / CHUNK;  // 2048 for N=2e6

    init_kernel<<<(G * DEPTH + 255) / 256, 256, 0, stream>>>(sumbuf, maxbuf, cntbuf, G);
    pool_kernel<<<nchunks, 256, 0, stream>>>(
        (const f4*)x, batch, sumbuf, maxbuf, cntbuf, N);
    mlp_kernel<<<(G + GPB - 1) / GPB, 256, 0, stream>>>(
        sumbuf, maxbuf, cntbuf, W1, b1, W2, b2, out, G);
}

// Round 6
// 287.208 us; speedup vs baseline: 1.0515x; 1.0515x over previous
//
#include <hip/hip_runtime.h>

#define DEPTH 128
#define GPB 16    // graphs per block in the MLP kernel
#define GRPB 8    // graphs per block in the pool kernel

typedef float f4 __attribute__((ext_vector_type(4)));

// Kernel 1: 512 blocks x 1024 threads; each block owns 8 consecutive graphs
// (~2 MB contiguous region) -> few long DRAM streams instead of 2048 short
// ones. 32 row-groups: a wave's 64 lanes cover two ADJACENT rows = one
// contiguous 1 KB per global_load_dwordx4.
__global__ __launch_bounds__(1024, 1) void pool_kernel(
    const f4* __restrict__ x4, const int* __restrict__ batch,
    float* __restrict__ pooled, int N, int G)
{
    const int tid = threadIdx.x;
    const int rg  = tid >> 5;   // row group 0..31
    const int d4  = tid & 31;   // float4 column 0..31
    const int g0  = blockIdx.x * GRPB;
    if (g0 >= G) return;

    __shared__ int sb[GRPB + 1];
    if (tid <= GRPB) {
        const int target = g0 + tid;   // start(target): first i with batch[i] >= target
        int lo = 0, hi = N;
        while (lo < hi) {
            int mid = (lo + hi) >> 1;
            if (batch[mid] < target) lo = mid + 1; else hi = mid;
        }
        sb[tid] = lo;
    }
    __syncthreads();

    __shared__ f4 redS[32][32];   // 16 KB
    __shared__ f4 redM[32][32];   // 16 KB

#define ACC(v, s, m) do { \
        (s) += (v); \
        (m).x = fmaxf((m).x, (v).x); (m).y = fmaxf((m).y, (v).y); \
        (m).z = fmaxf((m).z, (v).z); (m).w = fmaxf((m).w, (v).w); } while (0)

    for (int gi = 0; gi < GRPB; ++gi) {
        const int bs = sb[gi], be = sb[gi + 1];

        f4 sum0 = (f4)(0.f), sum1 = sum0, sum2 = sum0, sum3 = sum0;
        f4 mx0 = (f4)(-INFINITY), mx1 = mx0, mx2 = mx0, mx3 = mx0;

        int r = bs + rg;
        for (; r + 96 < be; r += 128) {
            f4 v0 = x4[(size_t)(r)      * 32 + d4];
            f4 v1 = x4[(size_t)(r + 32) * 32 + d4];
            f4 v2 = x4[(size_t)(r + 64) * 32 + d4];
            f4 v3 = x4[(size_t)(r + 96) * 32 + d4];
            ACC(v0, sum0, mx0); ACC(v1, sum1, mx1);
            ACC(v2, sum2, mx2); ACC(v3, sum3, mx3);
        }
        for (; r < be; r += 32) {
            f4 v = x4[(size_t)r * 32 + d4];
            ACC(v, sum0, mx0);
        }

        f4 sum = sum0 + sum1 + sum2 + sum3;
        f4 mx;
        mx.x = fmaxf(fmaxf(mx0.x, mx1.x), fmaxf(mx2.x, mx3.x));
        mx.y = fmaxf(fmaxf(mx0.y, mx1.y), fmaxf(mx2.y, mx3.y));
        mx.z = fmaxf(fmaxf(mx0.z, mx1.z), fmaxf(mx2.z, mx3.z));
        mx.w = fmaxf(fmaxf(mx0.w, mx1.w), fmaxf(mx2.w, mx3.w));

        redS[rg][d4] = sum;
        redM[rg][d4] = mx;
        __syncthreads();

        if (tid < 32) {
            f4 sr = redS[0][d4];
            f4 mr = redM[0][d4];
            #pragma unroll
            for (int i = 1; i < 32; ++i) {
                sr += redS[i][d4];
                f4 tm = redM[i][d4];
                mr.x = fmaxf(mr.x, tm.x); mr.y = fmaxf(mr.y, tm.y);
                mr.z = fmaxf(mr.z, tm.z); mr.w = fmaxf(mr.w, tm.w);
            }
            const int cnt = be - bs;
            const float inv = 1.0f / (float)(cnt > 1 ? cnt : 1);
            if (cnt == 0) mr = (f4)(0.f);
            f4 mean4 = sr * inv;
            f4* prow = reinterpret_cast<f4*>(pooled + (size_t)(g0 + gi) * 3 * DEPTH);
            prow[d4]      = mr;     // max   [0:128)
            prow[32 + d4] = mean4;  // mean  [128:256)
            prow[64 + d4] = sr;     // sum   [256:384)
        }
        __syncthreads();   // redS/redM reused next graph
    }
#undef ACC
}

// Kernel 2: MLP over pooled features, GPB graphs per block (weights amortized).
__global__ __launch_bounds__(256) void mlp_kernel(
    const float* __restrict__ pooled,
    const float* __restrict__ W1, const float* __restrict__ b1,
    const float* __restrict__ W2, const float* __restrict__ b2,
    float* __restrict__ out, int G)
{
    __shared__ float h[GPB][3 * DEPTH];   // 24 KB
    __shared__ float a[GPB][DEPTH];       // 8 KB
    const int tid = threadIdx.x;
    const int g0  = blockIdx.x * GPB;

    {
        const f4* p4 = reinterpret_cast<const f4*>(pooled + (size_t)g0 * 3 * DEPTH);
        f4* h4 = reinterpret_cast<f4*>(&h[0][0]);
        const int total = GPB * 3 * DEPTH / 4;   // 1536
        for (int i = tid; i < total; i += 256) h4[i] = p4[i];
    }
    __syncthreads();

    const int j  = tid & 127;               // output dim
    const int gh = (tid >> 7) * (GPB / 2);  // 0 or 8

    float acc[GPB / 2];
    #pragma unroll
    for (int i = 0; i < GPB / 2; ++i) acc[i] = b1[j];
    {
        const f4* w1r = reinterpret_cast<const f4*>(W1 + (size_t)j * 3 * DEPTH);
        for (int k = 0; k < 3 * DEPTH / 4; ++k) {
            f4 w = w1r[k];
            #pragma unroll
            for (int i = 0; i < GPB / 2; ++i) {
                f4 hv = reinterpret_cast<const f4*>(h[gh + i])[k];  // LDS broadcast
                acc[i] += w.x * hv.x + w.y * hv.y + w.z * hv.z + w.w * hv.w;
            }
        }
    }
    #pragma unroll
    for (int i = 0; i < GPB / 2; ++i)
        a[gh + i][j] = (acc[i] > 0.f) ? acc[i] : 0.01f * acc[i];
    __syncthreads();

    #pragma unroll
    for (int i = 0; i < GPB / 2; ++i) acc[i] = b2[j];
    {
        const f4* w2r = reinterpret_cast<const f4*>(W2 + (size_t)j * DEPTH);
        for (int k = 0; k < DEPTH / 4; ++k) {
            f4 w = w2r[k];
            #pragma unroll
            for (int i = 0; i < GPB / 2; ++i) {
                f4 av = reinterpret_cast<const f4*>(a[gh + i])[k];  // LDS broadcast
                acc[i] += w.x * av.x + w.y * av.y + w.z * av.z + w.w * av.w;
            }
        }
    }
    #pragma unroll
    for (int i = 0; i < GPB / 2; ++i) {
        const int g = g0 + gh + i;
        if (g < G) out[(size_t)g * DEPTH + j] = acc[i];
    }
}

extern "C" void kernel_launch(void* const* d_in, const int* in_sizes, int n_in,
                              void* d_out, int out_size, void* d_ws, size_t ws_size,
                              hipStream_t stream) {
    const float* x     = (const float*)d_in[0];
    const int*   batch = (const int*)d_in[1];
    const float* W1 = (const float*)d_in[3];
    const float* b1 = (const float*)d_in[4];
    const float* W2 = (const float*)d_in[5];
    const float* b2 = (const float*)d_in[6];
    float* out = (float*)d_out;

    const int N = in_sizes[0] / DEPTH;   // 2,000,000 nodes
    const int G = out_size / DEPTH;      // 4096 graphs

    float* pooled = (float*)d_ws;        // G * 384 floats, fully rewritten

    pool_kernel<<<(G + GRPB - 1) / GRPB, 1024, 0, stream>>>(
        (const f4*)x, batch, pooled, N, G);
    mlp_kernel<<<(G + GPB - 1) / GPB, 256, 0, stream>>>(
        pooled, W1, b1, W2, b2, out, G);
}